// Round 2
// baseline (189.632 us; speedup 1.0000x reference)
//
#include <hip/hip_runtime.h>
#include <hip/hip_bf16.h>

typedef unsigned short u16;
typedef float  f32x16 __attribute__((ext_vector_type(16)));
typedef short  bf16x8 __attribute__((ext_vector_type(8)));
typedef u16    u16x8  __attribute__((ext_vector_type(8)));

#define CDIM 1024
#define HW   16384

typedef const void __attribute__((address_space(1))) gvoid;
typedef void __attribute__((address_space(3))) svoid;

__device__ __forceinline__ u16 f2bf(float f) {
    unsigned u = __float_as_uint(f);
    u += 0x7fffu + ((u >> 16) & 1u);            // RNE
    return (u16)(u >> 16);
}
__device__ __forceinline__ float bf2f(u16 h) { return __uint_as_float(((unsigned)h) << 16); }

__device__ __forceinline__ f32x16 mfma32(bf16x8 a, bf16x8 b, f32x16 c) {
    return __builtin_amdgcn_mfma_f32_32x32x16_bf16(a, b, c, 0, 0, 0);
}

// ---------------- K1: x(f32) -> hi, lo (split bf16) + hiT (fused transpose) ----------------
__global__ __launch_bounds__(256) void k_convert(const float* __restrict__ x,
                                                 u16* __restrict__ hi, u16* __restrict__ lo,
                                                 u16* __restrict__ hiT)
{
    __shared__ u16 tile[64][72];
    const int pb = blockIdx.x;   // HW tile (0..255)
    const int cb = blockIdx.y;   // C tile  (0..15)
    const int tid = threadIdx.x;
#pragma unroll
    for (int pass = 0; pass < 4; ++pass) {
        const int i  = (tid >> 4) + (pass << 4);    // c-row in tile 0..63
        const int j4 = (tid & 15) << 2;             // p-col in tile
        const long gidx = (long)(cb * 64 + i) * HW + pb * 64 + j4;
        const float4 v = *(const float4*)(x + gidx);
        ushort4 h, l;
        h.x = f2bf(v.x); l.x = f2bf(v.x - bf2f(h.x));
        h.y = f2bf(v.y); l.y = f2bf(v.y - bf2f(h.y));
        h.z = f2bf(v.z); l.z = f2bf(v.z - bf2f(h.z));
        h.w = f2bf(v.w); l.w = f2bf(v.w - bf2f(h.w));
        *(ushort4*)(hi + gidx) = h;
        *(ushort4*)(lo + gidx) = l;
        tile[i][j4 + 0] = h.x; tile[i][j4 + 1] = h.y;
        tile[i][j4 + 2] = h.z; tile[i][j4 + 3] = h.w;
    }
    __syncthreads();
#pragma unroll
    for (int pass = 0; pass < 2; ++pass) {
        const int j  = (tid >> 3) + (pass << 5);    // p-row 0..63
        const int c8 = (tid & 7) << 3;
        u16x8 v;
#pragma unroll
        for (int q = 0; q < 8; ++q) v[q] = tile[c8 + q][j];
        *(u16x8*)(hiT + (long)(pb * 64 + j) * CDIM + cb * 64 + c8) = v;
    }
}

// ============ 256x256 8-phase GEMM (T2 swizzle + T3/T4 counted vmcnt + T5 setprio) ============
// A row-major (M x K, k-contiguous), B row-major (N x K, k-contiguous) -> C[M][N] = A.B^T
// EPI 0: write split-K partial C + ks*csplit.   EPI 1: C = gamma*acc + X.

// Stage one 128x64 bf16 half-tile (16 KB) via global_load_lds(16B), inverse-swizzled source.
// LDS stores element (r,c) at u16 index r*64 + (c ^ ((r&7)<<3))  [involution].
__device__ __forceinline__ void stage_half(const u16* __restrict__ gbase, long ldg,
                                           int rowhalf, int ktile, u16* seg, int tid)
{
    const int wv = tid >> 6;
#pragma unroll
    for (int q = 0; q < 2; ++q) {
        const int lin16 = (q << 9) + tid;          // 16B-granule index 0..1023
        const int r    = lin16 >> 3;               // row 0..127
        const int slot = lin16 & 7;                // 16B slot in 128B row
        const int gc   = (slot ^ (r & 7)) << 3;    // inverse-swizzled source col (elems)
        const u16* src = gbase + (long)((rowhalf << 7) + r) * ldg + (ktile << 6) + gc;
        u16* dst = seg + (q << 12) + (wv << 9);    // wave-uniform base; HW adds lane*16B
        __builtin_amdgcn_global_load_lds((gvoid*)src, (svoid*)dst, 16, 0, 0);
    }
}

__device__ __forceinline__ bf16x8 rd_frag(const u16* seg, int row, int kk, int lane)
{
    const int c = (kk << 4) + ((lane >> 5) << 3);  // element col within 64-wide K-tile
    return *(const bf16x8*)(seg + row * 64 + (c ^ ((row & 7) << 3)));
}

#define SBAR()  do { __builtin_amdgcn_sched_barrier(0); \
                     __builtin_amdgcn_s_barrier();      \
                     __builtin_amdgcn_sched_barrier(0); } while (0)

template<int EPI>
__global__ __launch_bounds__(512, 2) void k_gemm8(
    const u16* __restrict__ Amat, const u16* __restrict__ Bhi, const u16* __restrict__ Blo,
    long lda, long ldb, int kchunk, int nbn,
    float* __restrict__ C, long ldc, long csplit,
    const float* __restrict__ X, const float* __restrict__ gamma)
{
    __shared__ u16 sA[2][2][8192];   // [dbuf][rowhalf][128*64]
    __shared__ u16 sB[2][2][8192];

    const int tid  = threadIdx.x;
    const int lane = tid & 63;
    const int w    = tid >> 6;
    const int wm   = w >> 2;         // 0..1
    const int wn   = w & 3;          // 0..3
    const int l31  = lane & 31;

    const int ks   = blockIdx.y;
    const int nblk = gridDim.x;
    const int lin  = blockIdx.x;
    const int ti   = (lin & 7) * (nblk >> 3) + (lin >> 3);   // bijective XCD swizzle (nblk%8==0)
    const int bi   = ti / nbn, bn = ti % nbn;

    const u16* Ab = Amat + (long)bi * 256 * lda + (long)ks * kchunk;
    const u16* Bb;
    if (EPI == 0) {
        const int half = nbn >> 1;   // combined B: first half rows from Bhi, second from Blo
        Bb = (bn < half) ? (Bhi + (long)bn * 256 * ldb)
                         : (Blo + (long)(bn - half) * 256 * ldb);
    } else {
        Bb = Bhi + (long)bn * 256 * ldb;
    }
    Bb += (long)ks * kchunk;

    const int nkt = kchunk >> 6;

    f32x16 acc[4][2];
    {
        f32x16 z;
#pragma unroll
        for (int r = 0; r < 16; ++r) z[r] = 0.f;
#pragma unroll
        for (int f = 0; f < 4; ++f)
#pragma unroll
            for (int g = 0; g < 2; ++g) acc[f][g] = z;
    }

    // ---- prologue: A0(0), B1(0), B0(0), A1(0), A0(1), B1(1) ----
    stage_half(Ab, lda, 0, 0, sA[0][0], tid);
    stage_half(Bb, ldb, 1, 0, sB[0][1], tid);
    stage_half(Bb, ldb, 0, 0, sB[0][0], tid);
    stage_half(Ab, lda, 1, 0, sA[0][1], tid);
    if (nkt > 1) {
        stage_half(Ab, lda, 0, 1, sA[1][0], tid);
        stage_half(Bb, ldb, 1, 1, sB[1][1], tid);
    }

    bf16x8 Af[2][4], B0f[4], B1f[4];

    for (int u = 0; u < nkt; ++u) {
        const int db = u & 1;

        // -------- phase 0: quadrant (A-half0, B-half0) --------
        if (u >= nkt - 2) {
            asm volatile("s_waitcnt vmcnt(0)" ::: "memory");
            if (u + 1 < nkt) stage_half(Bb, ldb, 0, u + 1, sB[db ^ 1][0], tid);
        } else {
            stage_half(Bb, ldb, 0, u + 1, sB[db ^ 1][0], tid);
            asm volatile("s_waitcnt vmcnt(6)" ::: "memory");   // 3 half-tiles stay in flight
        }
        SBAR();
#pragma unroll
        for (int f = 0; f < 2; ++f)
#pragma unroll
            for (int kk = 0; kk < 4; ++kk)
                Af[f][kk] = rd_frag(sA[db][0], wm * 64 + f * 32 + l31, kk, lane);
#pragma unroll
        for (int kk = 0; kk < 4; ++kk)
            B0f[kk] = rd_frag(sB[db][0], wn * 32 + l31, kk, lane);
        __builtin_amdgcn_s_setprio(1);
#pragma unroll
        for (int kk = 0; kk < 4; ++kk) {
            acc[0][0] = mfma32(Af[0][kk], B0f[kk], acc[0][0]);
            acc[1][0] = mfma32(Af[1][kk], B0f[kk], acc[1][0]);
        }
        __builtin_amdgcn_s_setprio(0);
        SBAR();

        // -------- phase 1: (A-half0, B-half1); A frags retained --------
        if (u + 1 < nkt) stage_half(Ab, lda, 1, u + 1, sA[db ^ 1][1], tid);
#pragma unroll
        for (int kk = 0; kk < 4; ++kk)
            B1f[kk] = rd_frag(sB[db][1], wn * 32 + l31, kk, lane);
        __builtin_amdgcn_s_setprio(1);
#pragma unroll
        for (int kk = 0; kk < 4; ++kk) {
            acc[0][1] = mfma32(Af[0][kk], B1f[kk], acc[0][1]);
            acc[1][1] = mfma32(Af[1][kk], B1f[kk], acc[1][1]);
        }
        __builtin_amdgcn_s_setprio(0);
        SBAR();

        // -------- phase 2: (A-half1, B-half1); B1 frags retained --------
        if (u + 2 < nkt) stage_half(Ab, lda, 0, u + 2, sA[db][0], tid);
#pragma unroll
        for (int f = 0; f < 2; ++f)
#pragma unroll
            for (int kk = 0; kk < 4; ++kk)
                Af[f][kk] = rd_frag(sA[db][1], wm * 64 + f * 32 + l31, kk, lane);
        __builtin_amdgcn_s_setprio(1);
#pragma unroll
        for (int kk = 0; kk < 4; ++kk) {
            acc[2][1] = mfma32(Af[0][kk], B1f[kk], acc[2][1]);
            acc[3][1] = mfma32(Af[1][kk], B1f[kk], acc[3][1]);
        }
        __builtin_amdgcn_s_setprio(0);
        SBAR();

        // -------- phase 3: (A-half1, B-half0); A & B0 frags retained, no LDS reads --------
        if (u + 2 < nkt) stage_half(Bb, ldb, 1, u + 2, sB[db][1], tid);
        __builtin_amdgcn_s_setprio(1);
#pragma unroll
        for (int kk = 0; kk < 4; ++kk) {
            acc[2][0] = mfma32(Af[0][kk], B0f[kk], acc[2][0]);
            acc[3][0] = mfma32(Af[1][kk], B0f[kk], acc[3][0]);
        }
        __builtin_amdgcn_s_setprio(0);
        SBAR();
    }

    // -------- epilogue --------
    if (EPI == 0) {
        float* Cb = C + (long)ks * csplit;
#pragma unroll
        for (int f = 0; f < 4; ++f)
#pragma unroll
            for (int g = 0; g < 2; ++g)
#pragma unroll
                for (int r = 0; r < 16; ++r) {
                    const int row = bi * 256 + (f >> 1) * 128 + wm * 64 + (f & 1) * 32
                                    + (r & 3) + ((r >> 2) << 3) + ((lane >> 5) << 2);
                    const int col = bn * 256 + g * 128 + wn * 32 + l31;
                    Cb[(long)row * ldc + col] = acc[f][g][r];
                }
    } else {
        const float gm = gamma[0];
#pragma unroll
        for (int f = 0; f < 4; ++f)
#pragma unroll
            for (int g = 0; g < 2; ++g)
#pragma unroll
                for (int r = 0; r < 16; ++r) {
                    const int row = bi * 256 + (f >> 1) * 128 + wm * 64 + (f & 1) * 32
                                    + (r & 3) + ((r >> 2) << 3) + ((lane >> 5) << 2);
                    const int col = bn * 256 + g * 128 + wn * 32 + l31;
                    const long idx = (long)row * ldc + col;
                    C[idx] = gm * acc[f][g][r] + X[idx];
                }
    }
}

// ---------------- K2b: Esym = sum_ks (E1 + E2 + E2^T), E12[ks][1024][2048] ----------------
__global__ __launch_bounds__(256) void k_symmetrize(const float* __restrict__ E12,
                                                    float* __restrict__ Esym)
{
    __shared__ float tr[64][65];
    const int jb = blockIdx.x, ib = blockIdx.y, tid = threadIdx.x;
    float4 accv[4];
#pragma unroll
    for (int e4 = 0; e4 < 4; ++e4) {
        const int e = tid + (e4 << 8);
        const int i = e >> 4, j4 = (e & 15) << 2;
        float ax = 0, ay = 0, az = 0, aw = 0, bx = 0, by = 0, bz = 0, bw = 0;
#pragma unroll
        for (int ks = 0; ks < 8; ++ks) {
            const float* base = E12 + (long)ks * (1024 * 2048);
            float4 p1 = *(const float4*)(base + (long)(ib * 64 + i) * 2048 + jb * 64 + j4);
            float4 p2 = *(const float4*)(base + (long)(ib * 64 + i) * 2048 + 1024 + jb * 64 + j4);
            float4 p3 = *(const float4*)(base + (long)(jb * 64 + i) * 2048 + 1024 + ib * 64 + j4);
            ax += p1.x + p2.x; ay += p1.y + p2.y; az += p1.z + p2.z; aw += p1.w + p2.w;
            bx += p3.x; by += p3.y; bz += p3.z; bw += p3.w;
        }
        accv[e4] = make_float4(ax, ay, az, aw);
        tr[i][j4 + 0] = bx; tr[i][j4 + 1] = by; tr[i][j4 + 2] = bz; tr[i][j4 + 3] = bw;
    }
    __syncthreads();
#pragma unroll
    for (int e4 = 0; e4 < 4; ++e4) {
        const int e = tid + (e4 << 8);
        const int i = e >> 4, j4 = (e & 15) << 2;
        float4 o = accv[e4];
        o.x += tr[j4 + 0][i]; o.y += tr[j4 + 1][i]; o.z += tr[j4 + 2][i]; o.w += tr[j4 + 3][i];
        *(float4*)(Esym + (long)(ib * 64 + i) * CDIM + jb * 64 + j4) = o;
    }
}

// ---------------- K3: att = softmax(-E) rows, stored bf16 ----------------
__global__ __launch_bounds__(256) void k_softmax(const float* __restrict__ E, u16* __restrict__ att)
{
    __shared__ float red[4];
    __shared__ float bcast;
    const int row = blockIdx.x, tid = threadIdx.x;
    const float4 v = ((const float4*)(E + (long)row * CDIM))[tid];

    float m = fminf(fminf(v.x, v.y), fminf(v.z, v.w));
#pragma unroll
    for (int s = 32; s > 0; s >>= 1) m = fminf(m, __shfl_down(m, s));
    if ((tid & 63) == 0) red[tid >> 6] = m;
    __syncthreads();
    if (tid == 0) bcast = fminf(fminf(red[0], red[1]), fminf(red[2], red[3]));
    __syncthreads();
    m = bcast;  // row min of E == row max of -E

    const float px = expf(m - v.x), py = expf(m - v.y), pz = expf(m - v.z), pw = expf(m - v.w);
    float s4 = px + py + pz + pw;
#pragma unroll
    for (int s = 32; s > 0; s >>= 1) s4 += __shfl_down(s4, s);
    if ((tid & 63) == 0) red[tid >> 6] = s4;
    __syncthreads();
    if (tid == 0) bcast = red[0] + red[1] + red[2] + red[3];
    __syncthreads();
    const float inv = 1.0f / bcast;

    ushort4 o;
    o.x = f2bf(px * inv); o.y = f2bf(py * inv); o.z = f2bf(pz * inv); o.w = f2bf(pw * inv);
    ((ushort4*)(att + (long)row * CDIM))[tid] = o;
}

extern "C" void kernel_launch(void* const* d_in, const int* in_sizes, int n_in,
                              void* d_out, int out_size, void* d_ws, size_t ws_size,
                              hipStream_t stream)
{
    (void)in_sizes; (void)n_in; (void)out_size; (void)ws_size;
    const float* x = (const float*)d_in[0];
    const float* gamma = (const float*)d_in[1];
    float* out = (float*)d_out;
    char* ws = (char*)d_ws;

    // Workspace (102 MiB, proven to fit): hi | lo | hiT | Esym | att.
    // Split-K partials (64 MiB) live in d_out, fully overwritten by the final GEMM.
    u16*   hi   = (u16*)ws;                         // 32 MiB
    u16*   lo   = (u16*)(ws + (32ull << 20));       // 32 MiB
    u16*   hiT  = (u16*)(ws + (64ull << 20));       // 32 MiB
    float* Esym = (float*)(ws + (96ull << 20));     //  4 MiB
    u16*   att  = (u16*)(ws + (100ull << 20));      //  2 MiB
    float* E12  = out;                              // 64 MiB scratch (== out buffer)

    k_convert<<<dim3(256, 16), 256, 0, stream>>>(x, hi, lo, hiT);
    // Energy: combined GEMM  M=1024, N=2048 (hi||lo), K=16384, split-K=8.
    k_gemm8<0><<<dim3(32, 8), 512, 0, stream>>>(hi, hi, lo, (long)HW, (long)HW, 2048, 8,
                                                E12, 2048L, 1024L * 2048L, nullptr, nullptr);
    k_symmetrize<<<dim3(16, 16), 256, 0, stream>>>(E12, Esym);
    k_softmax<<<1024, 256, 0, stream>>>(Esym, att);
    // Out: GEMM  M=1024, N=16384, K=1024; epilogue gamma*acc + x.
    k_gemm8<1><<<dim3(256, 1), 512, 0, stream>>>(att, hiT, nullptr, 1024L, 1024L, 1024, 64,
                                                 out, (long)HW, 0L, x, gamma);
}